// Round 13
// baseline (506.106 us; speedup 1.0000x reference)
//
#include <hip/hip_runtime.h>
#include <math.h>

typedef unsigned short u16;
typedef unsigned int u32;
typedef short bf16x8 __attribute__((ext_vector_type(8)));
typedef float f32x4 __attribute__((ext_vector_type(4)));
typedef u16 u16x4 __attribute__((ext_vector_type(4)));
typedef u16 u16x8 __attribute__((ext_vector_type(8)));
typedef u32 u32x4 __attribute__((ext_vector_type(4)));

// ---------- bf16 <-> f32 helpers ----------
static __device__ __forceinline__ float b2f(u16 u) {
  union { u32 i; float f; } v; v.i = ((u32)u) << 16; return v.f;
}
static __device__ __forceinline__ u16 f2b(float f) {
  union { float f; u32 i; } v; v.f = f;
  u32 r = v.i + 0x7fffu + ((v.i >> 16) & 1u);
  return (u16)(r >> 16);
}
static __device__ __forceinline__ void cvt16(const float* src, u16* dst, int i) {
  f32x4 v = *(const f32x4*)(src + (size_t)i * 4);
  u16x4 w; w.x = f2b(v.x); w.y = f2b(v.y); w.z = f2b(v.z); w.w = f2b(v.w);
  *(u16x4*)(dst + (size_t)i * 4) = w;
}

// ---------- async global -> LDS, 16B per lane ----------
static __device__ __forceinline__ void g2l16(const void* g, void* l) {
  typedef __attribute__((address_space(1))) const void gvoid;
  typedef __attribute__((address_space(3))) void lvoid;
  __builtin_amdgcn_global_load_lds((gvoid*)g, (lvoid*)l, 16, 0, 0);
}

// =====================================================================
// Standalone weight convert (tier-2/3).
// =====================================================================
__global__ __launch_bounds__(256)
void wcvt_kernel(const float* __restrict__ src, u16* __restrict__ dst, int n4)
{
  for (int i = blockIdx.x * 256 + threadIdx.x; i < n4; i += gridDim.x * 256)
    cvt16(src, dst, i);
}

// =====================================================================
// prep: blocks 0..9215 LayerNorm; 9216..10239 wq cvt; 10240..11263 wkv cvt.
// =====================================================================
__global__ __launch_bounds__(256)
void prep_kernel(const float* __restrict__ x, const float* __restrict__ mv,
                 u16* __restrict__ xf, u16* __restrict__ xm,
                 const float* __restrict__ wq, u16* __restrict__ wqs,
                 const float* __restrict__ wkv, u16* __restrict__ wkvs)
{
  const int b = blockIdx.x, tid = threadIdx.x;
  if (b >= 9216) {
    if (b < 10240) {
      const int n4 = 3072 * 3072 / 4;
      for (int i = (b - 9216) * 256 + tid; i < n4; i += 1024 * 256) cvt16(wq, wqs, i);
    } else {
      const int n4 = 6144 * 3072 / 4;
      for (int i = (b - 10240) * 256 + tid; i < n4; i += 1024 * 256) cvt16(wkv, wkvs, i);
    }
    return;
  }
  const float* src; u16* dst;
  if (b < 8192) { src = x + (size_t)b * 3072;          dst = xf + (size_t)b * 3072; }
  else          { src = mv + (size_t)(b - 8192) * 3072; dst = xm + (size_t)(b - 8192) * 3072; }

  f32x4 vals[3];
  #pragma unroll
  for (int i = 0; i < 3; ++i) vals[i] = *(const f32x4*)(src + tid * 4 + i * 1024);

  float s1 = 0.f, s2 = 0.f;
  #pragma unroll
  for (int i = 0; i < 3; ++i) {
    f32x4 v = vals[i];
    s1 += v.x + v.y + v.z + v.w;
    s2 += v.x * v.x + v.y * v.y + v.z * v.z + v.w * v.w;
  }
  #pragma unroll
  for (int o = 32; o > 0; o >>= 1) { s1 += __shfl_down(s1, o); s2 += __shfl_down(s2, o); }
  __shared__ float r1[4], r2[4];
  const int wv = tid >> 6, ln = tid & 63;
  if (ln == 0) { r1[wv] = s1; r2[wv] = s2; }
  __syncthreads();
  const float t1 = r1[0] + r1[1] + r1[2] + r1[3];
  const float t2 = r2[0] + r2[1] + r2[2] + r2[3];
  const float mu = t1 * (1.f / 3072.f);
  const float rs = rsqrtf(t2 * (1.f / 3072.f) - mu * mu + 1e-6f);
  #pragma unroll
  for (int i = 0; i < 3; ++i) {
    f32x4 v = vals[i]; u16x4 w;
    w.x = f2b((v.x - mu) * rs); w.y = f2b((v.y - mu) * rs);
    w.z = f2b((v.z - mu) * rs); w.w = f2b((v.w - mu) * rs);
    *(u16x4*)(dst + tid * 4 + i * 1024) = w;
  }
}

// =====================================================================
// gemm192 (R9-verified, ~160us on 8192x3072x3072): 128x192 tile, BK=32,
// 4 waves (2x2), per-wave 64x96, 3-buf rotation, counted vmcnt(5),
// XOR-swizzled LDS via pre-swizzled global source, setprio, XCD swizzle.
// Grid (M/128)x(N/192); for M=8192,N=3072 -> 1024 = 2.0 generations.
// =====================================================================
template<int EPI, typename TOUT>
__global__ __launch_bounds__(256, 2)
void gemm192(const u16* __restrict__ A, const u16* __restrict__ Wb,
             const float* __restrict__ bias, const float* __restrict__ mask,
             TOUT* __restrict__ C, int M, int N, int K)
{
  __shared__ __align__(16) u16 L[30720];
  const int tid = threadIdx.x, wave = tid >> 6, lane = tid & 63;
  const int nwg = gridDim.x;
  const int tb = (blockIdx.x & 7) * (nwg >> 3) + (blockIdx.x >> 3);
  const int nbx = N / 192;
  const int brow = (tb / nbx) << 7;
  const int bcol = (tb % nbx) * 192;
  const int wr = wave >> 1, wc = wave & 1;

  const u16* gA = A + (size_t)brow * K;
  const u16* gB = Wb + (size_t)bcol * K;

  const int srow = tid >> 2;
  const int scol = 8 * ((lane & 3) ^ ((lane >> 3) & 3));
  const int rcoff = 8 * ((lane >> 4) ^ ((lane >> 1) & 3));
  const int lr = lane & 15;

  f32x4 acc[4][6] = {};

  auto STAGE = [&](int b, int tk) {
    u16* bufA = &L[b * 10240];
    u16* bufB = bufA + 4096;
    const u16* srcA = gA + tk + scol;
    const u16* srcB = gB + tk + scol;
    #pragma unroll
    for (int j = 0; j < 2; ++j)
      g2l16(srcA + (size_t)(j * 64 + srow) * K, bufA + (j * 64 + wave * 16) * 32);
    #pragma unroll
    for (int j = 0; j < 3; ++j)
      g2l16(srcB + (size_t)(j * 64 + srow) * K, bufB + (j * 64 + wave * 16) * 32);
  };

  auto COMPUTE = [&](int b) {
    const u16* bufA = &L[b * 10240];
    const u16* bufB = bufA + 4096;
    bf16x8 af[4], bfv[6];
    #pragma unroll
    for (int m = 0; m < 4; ++m)
      af[m] = *(const bf16x8*)&bufA[(wr * 64 + m * 16 + lr) * 32 + rcoff];
    #pragma unroll
    for (int n = 0; n < 6; ++n)
      bfv[n] = *(const bf16x8*)&bufB[(wc * 96 + n * 16 + lr) * 32 + rcoff];
    __builtin_amdgcn_s_setprio(1);
    #pragma unroll
    for (int m = 0; m < 4; ++m)
      #pragma unroll
      for (int n = 0; n < 6; ++n)
        acc[m][n] = __builtin_amdgcn_mfma_f32_16x16x32_bf16(af[m], bfv[n], acc[m][n], 0, 0, 0);
    __builtin_amdgcn_s_setprio(0);
  };

  STAGE(0, 0);
  STAGE(1, 32);
  asm volatile("s_waitcnt vmcnt(5)" ::: "memory");
  __builtin_amdgcn_s_barrier();
  __builtin_amdgcn_sched_barrier(0);

  const int NT = K >> 5;
  int cur = 0;
  for (int t = 0; t < NT; ++t) {
    const bool pf = (t + 2) < NT;
    if (pf) {
      int nb = cur + 2; if (nb >= 3) nb -= 3;
      STAGE(nb, (t + 2) << 5);
    }
    COMPUTE(cur);
    if (pf) asm volatile("s_waitcnt vmcnt(5)" ::: "memory");
    else    asm volatile("s_waitcnt vmcnt(0)" ::: "memory");
    __builtin_amdgcn_s_barrier();
    __builtin_amdgcn_sched_barrier(0);
    if (++cur == 3) cur = 0;
  }

  #pragma unroll
  for (int m = 0; m < 4; ++m) {
    const int row = brow + wr * 64 + m * 16 + ((lane >> 4) << 2);
    #pragma unroll
    for (int n = 0; n < 6; ++n) {
      const int col = bcol + wc * 96 + n * 16 + lr;
      const float bv = bias[col];
      #pragma unroll
      for (int i = 0; i < 4; ++i) {
        float v = acc[m][n][i] + bv;
        if (EPI == 1) v *= mask[row + i];
        if constexpr (__is_same(TOUT, u16))
          C[(size_t)(row + i) * N + col] = f2b(v);
        else
          C[(size_t)(row + i) * N + col] = v;
      }
    }
  }
}

// =====================================================================
// gemm256 (R5-verified): 256x128 tile, BK=32, 4 waves, 3-buf rotation,
// counted vmcnt(6). Used for the KV GEMM (small M).
// =====================================================================
template<int EPI, typename TOUT>
__global__ __launch_bounds__(256, 2)
void gemm256(const u16* __restrict__ A, const u16* __restrict__ Wb,
             const float* __restrict__ bias, const float* __restrict__ mask,
             TOUT* __restrict__ C, int M, int N, int K)
{
  __shared__ __align__(16) u16 L[36864];
  const int tid = threadIdx.x, wave = tid >> 6, lane = tid & 63;

  const int nwg = gridDim.x;
  const int bid = (blockIdx.x & 7) * (nwg >> 3) + (blockIdx.x >> 3);
  const int nbx = N >> 7;
  const int brow = (bid / nbx) << 8;
  const int bcol = (bid % nbx) << 7;
  const int wr = wave >> 1, wc = wave & 1;

  const u16* gA = A + (size_t)brow * K;
  const u16* gB = Wb + (size_t)bcol * K;

  const int srow = tid >> 2;
  const int scol = 8 * ((lane & 3) ^ ((lane >> 3) & 3));
  const int rcoff = 8 * ((lane >> 4) ^ ((lane >> 1) & 3));

  f32x4 acc[8][4] = {};

  auto STAGE = [&](int b, int tk) {
    u16* bufA = &L[b * 12288];
    u16* bufB = bufA + 8192;
    const u16* srcA = gA + tk + scol;
    const u16* srcB = gB + tk + scol;
    #pragma unroll
    for (int j = 0; j < 4; ++j)
      g2l16(srcA + (size_t)(j * 64 + srow) * K, bufA + (j * 64 + wave * 16) * 32);
    #pragma unroll
    for (int j = 0; j < 2; ++j)
      g2l16(srcB + (size_t)(j * 64 + srow) * K, bufB + (j * 64 + wave * 16) * 32);
  };

  auto COMPUTE = [&](int b) {
    const u16* bufA = &L[b * 12288];
    const u16* bufB = bufA + 8192;
    bf16x8 af[8], bfv[4];
    #pragma unroll
    for (int m = 0; m < 8; ++m)
      af[m] = *(const bf16x8*)&bufA[(wr * 128 + m * 16 + (lane & 15)) * 32 + rcoff];
    #pragma unroll
    for (int n = 0; n < 4; ++n)
      bfv[n] = *(const bf16x8*)&bufB[(wc * 64 + n * 16 + (lane & 15)) * 32 + rcoff];
    __builtin_amdgcn_s_setprio(1);
    #pragma unroll
    for (int m = 0; m < 8; ++m)
      #pragma unroll
      for (int n = 0; n < 4; ++n)
        acc[m][n] = __builtin_amdgcn_mfma_f32_16x16x32_bf16(af[m], bfv[n], acc[m][n], 0, 0, 0);
    __builtin_amdgcn_s_setprio(0);
  };

  STAGE(0, 0);
  STAGE(1, 32);
  asm volatile("s_waitcnt vmcnt(6)" ::: "memory");
  __builtin_amdgcn_s_barrier();
  __builtin_amdgcn_sched_barrier(0);

  const int NT = K >> 5;
  int cur = 0;
  for (int t = 0; t < NT; ++t) {
    const bool pf = (t + 2) < NT;
    if (pf) {
      int nb = cur + 2; if (nb >= 3) nb -= 3;
      STAGE(nb, (t + 2) << 5);
    }
    COMPUTE(cur);
    if (pf) asm volatile("s_waitcnt vmcnt(6)" ::: "memory");
    else    asm volatile("s_waitcnt vmcnt(0)" ::: "memory");
    __builtin_amdgcn_s_barrier();
    __builtin_amdgcn_sched_barrier(0);
    if (++cur == 3) cur = 0;
  }

  #pragma unroll
  for (int m = 0; m < 8; ++m) {
    const int row = brow + wr * 128 + m * 16 + ((lane >> 4) << 2);
    #pragma unroll
    for (int n = 0; n < 4; ++n) {
      const int col = bcol + wc * 64 + n * 16 + (lane & 15);
      const float bv = bias[col];
      #pragma unroll
      for (int i = 0; i < 4; ++i) {
        float v = acc[m][n][i] + bv;
        if (EPI == 1) v *= mask[row + i];
        if constexpr (__is_same(TOUT, u16))
          C[(size_t)(row + i) * N + col] = f2b(v);
        else
          C[(size_t)(row + i) * N + col] = v;
      }
    }
  }
}

// =====================================================================
// Fallback mixed GEMM (W fp32 reg-staged cvt) — tier-3 only.
// =====================================================================
template<int EPI, typename TOUT>
__global__ __launch_bounds__(256)
void gemm_mixed(const u16* __restrict__ A, const float* __restrict__ W,
                const float* __restrict__ bias, const float* __restrict__ mask,
                TOUT* __restrict__ C, int M, int N, int K)
{
  __shared__ __align__(16) u16 lA[4096];
  __shared__ __align__(16) u16 lB[4096];
  const int tid = threadIdx.x, wave = tid >> 6, lane = tid & 63;
  const int nbx = N >> 7;
  const int brow = (blockIdx.x / nbx) << 7;
  const int bcol = (blockIdx.x % nbx) << 7;
  const int wr = wave >> 1, wc = wave & 1;

  f32x4 acc[4][4] = {};
  const u16* gA = A + (size_t)brow * K;
  const float* gB = W + (size_t)bcol * K;
  const int br = tid >> 1, bk0 = (tid & 1) << 4;
  const float* bsrc0 = gB + (size_t)br * K + bk0;
  u16* bdst = &lB[br * 32 + bk0];

  for (int tk = 0; tk < K; tk += 32) {
    #pragma unroll
    for (int j = 0; j < 2; ++j) {
      const int c = j * 256 + wave * 64 + lane;
      const int r = c >> 2, k8 = (c & 3) << 3;
      g2l16(gA + (size_t)r * K + tk + k8, (char*)lA + (size_t)(j * 256 + wave * 64) * 16);
    }
    {
      const float* src = bsrc0 + tk;
      #pragma unroll
      for (int j = 0; j < 4; ++j) {
        f32x4 v = *(const f32x4*)(src + 4 * j);
        u16x4 w; w.x = f2b(v.x); w.y = f2b(v.y); w.z = f2b(v.z); w.w = f2b(v.w);
        *(u16x4*)(bdst + 4 * j) = w;
      }
    }
    __syncthreads();

    bf16x8 af[4], bfr[4];
    #pragma unroll
    for (int m = 0; m < 4; ++m)
      af[m] = *(const bf16x8*)&lA[(wr * 64 + m * 16 + (lane & 15)) * 32 + ((lane >> 4) << 3)];
    #pragma unroll
    for (int n = 0; n < 4; ++n)
      bfr[n] = *(const bf16x8*)&lB[(wc * 64 + n * 16 + (lane & 15)) * 32 + ((lane >> 4) << 3)];
    #pragma unroll
    for (int m = 0; m < 4; ++m)
      #pragma unroll
      for (int n = 0; n < 4; ++n)
        acc[m][n] = __builtin_amdgcn_mfma_f32_16x16x32_bf16(af[m], bfr[n], acc[m][n], 0, 0, 0);
    __syncthreads();
  }

  #pragma unroll
  for (int m = 0; m < 4; ++m) {
    const int row = brow + wr * 64 + m * 16 + ((lane >> 4) << 2);
    #pragma unroll
    for (int n = 0; n < 4; ++n) {
      const int col = bcol + wc * 64 + n * 16 + (lane & 15);
      const float bv = bias[col];
      #pragma unroll
      for (int i = 0; i < 4; ++i) {
        float v = acc[m][n][i] + bv;
        if (EPI == 1) v *= mask[row + i];
        if constexpr (__is_same(TOUT, u16))
          C[(size_t)(row + i) * N + col] = f2b(v);
        else
          C[(size_t)(row + i) * N + col] = v;
      }
    }
  }
}

// =====================================================================
// attn_wcvt: blocks 0..767 MFMA attention (verified R7 body);
// blocks 768..1791 wo fp32->bf16.
// =====================================================================
__global__ __launch_bounds__(256)
void attn_wcvt(const u16* __restrict__ qb, const u16* __restrict__ kvb,
               const float* __restrict__ qw, const float* __restrict__ kw,
               u16* __restrict__ attnb,
               const float* __restrict__ wo, u16* __restrict__ wos)
{
  __shared__ __align__(16) u16 Kn[32 * 136];
  __shared__ __align__(16) u16 Vt[128 * 40];
  __shared__ __align__(16) u16 Pl[256 * 40];
  __shared__ __align__(16) u16 Ol[4][16 * 136];
  const int tid = threadIdx.x;
  if (blockIdx.x >= 768) {
    const int n4 = 3072 * 3072 / 4;
    for (int i = (blockIdx.x - 768) * 256 + tid; i < n4; i += 1024 * 256)
      cvt16(wo, wos, i);
    return;
  }
  const int wave = tid >> 6, lane = tid & 63;
  const int h = blockIdx.x % 24;
  const int bt = blockIdx.x / 24;

  {
    const int n = tid >> 3, sub = tid & 7;
    const size_t base = (size_t)(bt * 32 + n) * 6144 + (size_t)h * 128;
    const u16* kp = kvb + base + sub * 16;
    u16x8 k0 = *(const u16x8*)kp;
    u16x8 k1 = *(const u16x8*)(kp + 8);
    float kv_[16]; float ss = 0.f;
    #pragma unroll
    for (int j = 0; j < 8; ++j) { kv_[j] = b2f(k0[j]); kv_[8 + j] = b2f(k1[j]); }
    #pragma unroll
    for (int j = 0; j < 16; ++j) ss += kv_[j] * kv_[j];
    ss += __shfl_xor(ss, 1); ss += __shfl_xor(ss, 2); ss += __shfl_xor(ss, 4);
    const float krs = rsqrtf(ss * (1.f / 128.f) + 1e-6f);
    u16x8 w0, w1;
    #pragma unroll
    for (int j = 0; j < 8; ++j) {
      const int d = sub * 16 + j;
      w0[j] = f2b(kv_[j] * krs * kw[d] * qw[d]);
      w1[j] = f2b(kv_[8 + j] * krs * kw[d + 8] * qw[d + 8]);
    }
    *(u16x8*)&Kn[n * 136 + sub * 16] = w0;
    *(u16x8*)&Kn[n * 136 + sub * 16 + 8] = w1;
  }
  {
    const int k = tid >> 3, dc = (tid & 7) * 16;
    const u16* vp = kvb + (size_t)(bt * 32 + k) * 6144 + (size_t)h * 128 + 3072 + dc;
    u16x8 v0 = *(const u16x8*)vp;
    u16x8 v1 = *(const u16x8*)(vp + 8);
    #pragma unroll
    for (int j = 0; j < 8; ++j) {
      Vt[(dc + j) * 40 + k] = v0[j];
      Vt[(dc + 8 + j) * 40 + k] = v1[j];
    }
  }
  __syncthreads();

  const int q0 = wave * 64;
  const int lr = lane & 15, lg = lane >> 4;

  for (int m = 0; m < 4; ++m) {
    const int qrow = q0 + m * 16 + lr;
    const u16* qp = qb + (size_t)(bt * 256 + qrow) * 3072 + (size_t)h * 128 + lg * 8;
    bf16x8 qf[4];
    #pragma unroll
    for (int k = 0; k < 4; ++k) qf[k] = *(const bf16x8*)(qp + k * 32);
    float ss = 0.f;
    #pragma unroll
    for (int k = 0; k < 4; ++k)
      #pragma unroll
      for (int j = 0; j < 8; ++j) { const float f = b2f((u16)qf[k][j]); ss += f * f; }
    ss += __shfl_xor(ss, 16); ss += __shfl_xor(ss, 32);
    const float qsc = rsqrtf(ss * (1.f / 128.f) + 1e-6f) * 0.08838834764831845f;
    #pragma unroll
    for (int k = 0; k < 4; ++k)
      #pragma unroll
      for (int j = 0; j < 8; ++j)
        qf[k][j] = (short)f2b(b2f((u16)qf[k][j]) * qsc);

    f32x4 s0 = {0.f, 0.f, 0.f, 0.f}, s1 = {0.f, 0.f, 0.f, 0.f};
    #pragma unroll
    for (int k = 0; k < 4; ++k) {
      bf16x8 kb0 = *(const bf16x8*)&Kn[(lr) * 136 + k * 32 + lg * 8];
      bf16x8 kb1 = *(const bf16x8*)&Kn[(16 + lr) * 136 + k * 32 + lg * 8];
      s0 = __builtin_amdgcn_mfma_f32_16x16x32_bf16(qf[k], kb0, s0, 0, 0, 0);
      s1 = __builtin_amdgcn_mfma_f32_16x16x32_bf16(qf[k], kb1, s1, 0, 0, 0);
    }

    float mx[4], sm[4], e0[4], e1[4];
    #pragma unroll
    for (int i = 0; i < 4; ++i) mx[i] = fmaxf(s0[i], s1[i]);
    #pragma unroll
    for (int o = 1; o <= 8; o <<= 1)
      #pragma unroll
      for (int i = 0; i < 4; ++i) mx[i] = fmaxf(mx[i], __shfl_xor(mx[i], o));
    #pragma unroll
    for (int i = 0; i < 4; ++i) {
      e0[i] = __expf(s0[i] - mx[i]);
      e1[i] = __expf(s1[i] - mx[i]);
      sm[i] = e0[i] + e1[i];
    }
    #pragma unroll
    for (int o = 1; o <= 8; o <<= 1)
      #pragma unroll
      for (int i = 0; i < 4; ++i) sm[i] += __shfl_xor(sm[i], o);
    #pragma unroll
    for (int i = 0; i < 4; ++i) {
      const float inv = 1.f / sm[i];
      const int pr = (q0 + m * 16 + lg * 4 + i) * 40;
      Pl[pr + lr] = f2b(e0[i] * inv);
      Pl[pr + 16 + lr] = f2b(e1[i] * inv);
    }
    asm volatile("s_waitcnt lgkmcnt(0)" ::: "memory");
    __builtin_amdgcn_sched_barrier(0);

    bf16x8 pf = *(const bf16x8*)&Pl[(q0 + m * 16 + lr) * 40 + lg * 8];
    f32x4 o_[8];
    #pragma unroll
    for (int n = 0; n < 8; ++n) {
      bf16x8 vb = *(const bf16x8*)&Vt[(n * 16 + lr) * 40 + lg * 8];
      o_[n] = __builtin_amdgcn_mfma_f32_16x16x32_bf16(
                pf, vb, (f32x4){0.f, 0.f, 0.f, 0.f}, 0, 0, 0);
    }

    u16* ow = &Ol[wave][0];
    #pragma unroll
    for (int n = 0; n < 8; ++n)
      #pragma unroll
      for (int i = 0; i < 4; ++i)
        ow[(lg * 4 + i) * 136 + n * 16 + lr] = f2b(o_[n][i]);
    asm volatile("s_waitcnt lgkmcnt(0)" ::: "memory");
    __builtin_amdgcn_sched_barrier(0);
    const int r = lane >> 2, cc = (lane & 3) * 32;
    u16* gout = attnb + (size_t)(bt * 256 + q0 + m * 16 + r) * 3072 + (size_t)h * 128 + cc;
    #pragma unroll
    for (int c = 0; c < 4; ++c)
      *(u16x8*)(gout + c * 8) = *(const u16x8*)&ow[r * 136 + cc + c * 8];
    asm volatile("s_waitcnt lgkmcnt(0)" ::: "memory");
    __builtin_amdgcn_sched_barrier(0);
  }
}

// =====================================================================
extern "C" void kernel_launch(void* const* d_in, const int* in_sizes, int n_in,
                              void* d_out, int out_size, void* d_ws, size_t ws_size,
                              hipStream_t stream) {
  const float* x    = (const float*)d_in[0];
  const float* mv   = (const float*)d_in[1];
  const float* mask = (const float*)d_in[2];
  const float* wkv  = (const float*)d_in[3];
  const float* bkv  = (const float*)d_in[4];
  const float* wq   = (const float*)d_in[5];
  const float* bq   = (const float*)d_in[6];
  const float* wo   = (const float*)d_in[7];
  const float* bo   = (const float*)d_in[8];
  const float* qnw  = (const float*)d_in[9];
  const float* knw  = (const float*)d_in[10];
  float* out = (float*)d_out;

  char* ws = (char*)d_ws;

  if (ws_size >= 176160768u) {
    // tier-1 layout
    u16* wqs  = (u16*)(ws);                  // 3072x3072 bf16
    u16* wkvs = (u16*)(ws + 18874368);       // 6144x3072 bf16
    u16* xf   = (u16*)(ws + 56623104);       // 8192x3072 bf16
    u16* xm   = (u16*)(ws + 106954752);      // 1024x3072 bf16
    u16* qbuf = (u16*)(ws + 113246208);      // 8192x3072 bf16
    u16* kvb  = (u16*)(ws + 163577856);      // 1024x6144 bf16 (end 176,160,768)
    u16* wos  = wqs;                         // reuse (dead after Q-GEMM)

    prep_kernel<<<11264, 256, 0, stream>>>(x, mv, xf, xm, wq, wqs, wkv, wkvs);
    gemm192<0, u16><<<1024, 256, 0, stream>>>(xf, wqs, bq, nullptr, qbuf, 8192, 3072, 3072);
    gemm256<0, u16><<<192, 256, 0, stream>>>(xm, wkvs, bkv, nullptr, kvb, 1024, 6144, 3072);
    attn_wcvt<<<1792, 256, 0, stream>>>(qbuf, kvb, qnw, knw, xf, wo, wos);
    gemm192<1, float><<<1024, 256, 0, stream>>>(xf, wos, bo, mask, out, 8192, 3072, 3072);
  } else if (ws_size >= 157286400u) {
    // tier-2
    u16* xf    = (u16*)(ws);
    u16* xm    = (u16*)(ws + 50331648);
    u16* qbuf  = (u16*)(ws + 56623104);
    u16* kvb   = (u16*)(ws + 106954752);
    u16* wslab = (u16*)(ws + 119537664);

    prep_kernel<<<9216, 256, 0, stream>>>(x, mv, xf, xm, wq, wslab, wkv, wslab);
    wcvt_kernel<<<2048, 256, 0, stream>>>(wq, wslab, 3072 * 3072 / 4);
    gemm192<0, u16><<<1024, 256, 0, stream>>>(xf, wslab, bq, nullptr, qbuf, 8192, 3072, 3072);
    wcvt_kernel<<<2048, 256, 0, stream>>>(wkv, wslab, 6144 * 3072 / 4);
    gemm256<0, u16><<<192, 256, 0, stream>>>(xm, wslab, bkv, nullptr, kvb, 1024, 6144, 3072);
    attn_wcvt<<<768, 256, 0, stream>>>(qbuf, kvb, qnw, knw, xf, wo, wslab);
    wcvt_kernel<<<2048, 256, 0, stream>>>(wo, wslab, 3072 * 3072 / 4);
    gemm192<1, float><<<1024, 256, 0, stream>>>(xf, wslab, bo, mask, out, 8192, 3072, 3072);
  } else {
    // tier-3: mixed fallback
    u16* xf   = (u16*)(ws);
    u16* xm   = (u16*)(ws + 50331648);
    u16* qbuf = (u16*)(ws + 56623104);
    u16* kvb  = (u16*)(ws + 106954752);

    prep_kernel<<<9216, 256, 0, stream>>>(x, mv, xf, xm, wq, xf, wkv, xf);
    gemm_mixed<0, u16><<<1536, 256, 0, stream>>>(xf, wq, bq, nullptr, qbuf, 8192, 3072, 3072);
    gemm_mixed<0, u16><<<384, 256, 0, stream>>>(xm, wkv, bkv, nullptr, kvb, 1024, 6144, 3072);
    attn_wcvt<<<768, 256, 0, stream>>>(qbuf, kvb, qnw, knw, xf, wo, xf);
    gemm_mixed<1, float><<<1536, 256, 0, stream>>>(xf, wo, bo, mask, out, 8192, 3072, 3072);
  }
}

// Round 14
// 461.335 us; speedup vs baseline: 1.0970x; 1.0970x over previous
//
#include <hip/hip_runtime.h>
#include <math.h>

typedef unsigned short u16;
typedef unsigned int u32;
typedef short bf16x8 __attribute__((ext_vector_type(8)));
typedef float f32x4 __attribute__((ext_vector_type(4)));
typedef u16 u16x4 __attribute__((ext_vector_type(4)));
typedef u16 u16x8 __attribute__((ext_vector_type(8)));
typedef u32 u32x4 __attribute__((ext_vector_type(4)));

// ---------- bf16 <-> f32 helpers ----------
static __device__ __forceinline__ float b2f(u16 u) {
  union { u32 i; float f; } v; v.i = ((u32)u) << 16; return v.f;
}
static __device__ __forceinline__ u16 f2b(float f) {
  union { float f; u32 i; } v; v.f = f;
  u32 r = v.i + 0x7fffu + ((v.i >> 16) & 1u);
  return (u16)(r >> 16);
}
static __device__ __forceinline__ void cvt16(const float* src, u16* dst, int i) {
  f32x4 v = *(const f32x4*)(src + (size_t)i * 4);
  u16x4 w; w.x = f2b(v.x); w.y = f2b(v.y); w.z = f2b(v.z); w.w = f2b(v.w);
  *(u16x4*)(dst + (size_t)i * 4) = w;
}

// ---------- async global -> LDS, 16B per lane ----------
static __device__ __forceinline__ void g2l16(const void* g, void* l) {
  typedef __attribute__((address_space(1))) const void gvoid;
  typedef __attribute__((address_space(3))) void lvoid;
  __builtin_amdgcn_global_load_lds((gvoid*)g, (lvoid*)l, 16, 0, 0);
}

// =====================================================================
// Standalone weight convert (tier-2/3).
// =====================================================================
__global__ __launch_bounds__(256)
void wcvt_kernel(const float* __restrict__ src, u16* __restrict__ dst, int n4)
{
  for (int i = blockIdx.x * 256 + threadIdx.x; i < n4; i += gridDim.x * 256)
    cvt16(src, dst, i);
}

// =====================================================================
// prep: blocks 0..9215 LayerNorm; 9216..10239 wq cvt; 10240..11263 wkv cvt.
// =====================================================================
__global__ __launch_bounds__(256)
void prep_kernel(const float* __restrict__ x, const float* __restrict__ mv,
                 u16* __restrict__ xf, u16* __restrict__ xm,
                 const float* __restrict__ wq, u16* __restrict__ wqs,
                 const float* __restrict__ wkv, u16* __restrict__ wkvs)
{
  const int b = blockIdx.x, tid = threadIdx.x;
  if (b >= 9216) {
    if (b < 10240) {
      const int n4 = 3072 * 3072 / 4;
      for (int i = (b - 9216) * 256 + tid; i < n4; i += 1024 * 256) cvt16(wq, wqs, i);
    } else {
      const int n4 = 6144 * 3072 / 4;
      for (int i = (b - 10240) * 256 + tid; i < n4; i += 1024 * 256) cvt16(wkv, wkvs, i);
    }
    return;
  }
  const float* src; u16* dst;
  if (b < 8192) { src = x + (size_t)b * 3072;          dst = xf + (size_t)b * 3072; }
  else          { src = mv + (size_t)(b - 8192) * 3072; dst = xm + (size_t)(b - 8192) * 3072; }

  f32x4 vals[3];
  #pragma unroll
  for (int i = 0; i < 3; ++i) vals[i] = *(const f32x4*)(src + tid * 4 + i * 1024);

  float s1 = 0.f, s2 = 0.f;
  #pragma unroll
  for (int i = 0; i < 3; ++i) {
    f32x4 v = vals[i];
    s1 += v.x + v.y + v.z + v.w;
    s2 += v.x * v.x + v.y * v.y + v.z * v.z + v.w * v.w;
  }
  #pragma unroll
  for (int o = 32; o > 0; o >>= 1) { s1 += __shfl_down(s1, o); s2 += __shfl_down(s2, o); }
  __shared__ float r1[4], r2[4];
  const int wv = tid >> 6, ln = tid & 63;
  if (ln == 0) { r1[wv] = s1; r2[wv] = s2; }
  __syncthreads();
  const float t1 = r1[0] + r1[1] + r1[2] + r1[3];
  const float t2 = r2[0] + r2[1] + r2[2] + r2[3];
  const float mu = t1 * (1.f / 3072.f);
  const float rs = rsqrtf(t2 * (1.f / 3072.f) - mu * mu + 1e-6f);
  #pragma unroll
  for (int i = 0; i < 3; ++i) {
    f32x4 v = vals[i]; u16x4 w;
    w.x = f2b((v.x - mu) * rs); w.y = f2b((v.y - mu) * rs);
    w.z = f2b((v.z - mu) * rs); w.w = f2b((v.w - mu) * rs);
    *(u16x4*)(dst + tid * 4 + i * 1024) = w;
  }
}

// =====================================================================
// g256_body: R5-verified pipelined GEMM body. 256x128 tile, BK=32,
// 4 waves (2x2), 3-buf LDS rotation (72 KB), counted vmcnt(6),
// XOR-swizzled LDS via pre-swizzled global source, setprio.
// Measured: 177 us / 873 TF on 8192x3072x3072, bank conflicts 0.
// =====================================================================
template<int EPI, typename TOUT>
static __device__ __forceinline__ void g256_body(
    const u16* __restrict__ A, const u16* __restrict__ Wb,
    const float* __restrict__ bias, const float* __restrict__ mask,
    TOUT* __restrict__ C, int N, int K, int tb, u16* L)
{
  const int tid = threadIdx.x, wave = tid >> 6, lane = tid & 63;
  const int nbx = N >> 7;
  const int brow = (tb / nbx) << 8;
  const int bcol = (tb % nbx) << 7;
  const int wr = wave >> 1, wc = wave & 1;

  const u16* gA = A + (size_t)brow * K;
  const u16* gB = Wb + (size_t)bcol * K;

  const int srow = tid >> 2;
  const int scol = 8 * ((lane & 3) ^ ((lane >> 3) & 3));
  const int rcoff = 8 * ((lane >> 4) ^ ((lane >> 1) & 3));

  f32x4 acc[8][4] = {};

  auto STAGE = [&](int b, int tk) {
    u16* bufA = &L[b * 12288];
    u16* bufB = bufA + 8192;
    const u16* srcA = gA + tk + scol;
    const u16* srcB = gB + tk + scol;
    #pragma unroll
    for (int j = 0; j < 4; ++j)
      g2l16(srcA + (size_t)(j * 64 + srow) * K, bufA + (j * 64 + wave * 16) * 32);
    #pragma unroll
    for (int j = 0; j < 2; ++j)
      g2l16(srcB + (size_t)(j * 64 + srow) * K, bufB + (j * 64 + wave * 16) * 32);
  };

  auto COMPUTE = [&](int b) {
    const u16* bufA = &L[b * 12288];
    const u16* bufB = bufA + 8192;
    bf16x8 af[8], bfv[4];
    #pragma unroll
    for (int m = 0; m < 8; ++m)
      af[m] = *(const bf16x8*)&bufA[(wr * 128 + m * 16 + (lane & 15)) * 32 + rcoff];
    #pragma unroll
    for (int n = 0; n < 4; ++n)
      bfv[n] = *(const bf16x8*)&bufB[(wc * 64 + n * 16 + (lane & 15)) * 32 + rcoff];
    __builtin_amdgcn_s_setprio(1);
    #pragma unroll
    for (int m = 0; m < 8; ++m)
      #pragma unroll
      for (int n = 0; n < 4; ++n)
        acc[m][n] = __builtin_amdgcn_mfma_f32_16x16x32_bf16(af[m], bfv[n], acc[m][n], 0, 0, 0);
    __builtin_amdgcn_s_setprio(0);
  };

  STAGE(0, 0);
  STAGE(1, 32);
  asm volatile("s_waitcnt vmcnt(6)" ::: "memory");
  __builtin_amdgcn_s_barrier();
  __builtin_amdgcn_sched_barrier(0);

  const int NT = K >> 5;
  int cur = 0;
  for (int t = 0; t < NT; ++t) {
    const bool pf = (t + 2) < NT;
    if (pf) {
      int nb = cur + 2; if (nb >= 3) nb -= 3;
      STAGE(nb, (t + 2) << 5);
    }
    COMPUTE(cur);
    if (pf) asm volatile("s_waitcnt vmcnt(6)" ::: "memory");
    else    asm volatile("s_waitcnt vmcnt(0)" ::: "memory");
    __builtin_amdgcn_s_barrier();
    __builtin_amdgcn_sched_barrier(0);
    if (++cur == 3) cur = 0;
  }

  #pragma unroll
  for (int m = 0; m < 8; ++m) {
    const int row = brow + wr * 128 + m * 16 + ((lane >> 4) << 2);
    #pragma unroll
    for (int n = 0; n < 4; ++n) {
      const int col = bcol + wc * 64 + n * 16 + (lane & 15);
      const float bv = bias[col];
      #pragma unroll
      for (int i = 0; i < 4; ++i) {
        float v = acc[m][n][i] + bv;
        if (EPI == 1) v *= mask[row + i];
        if constexpr (__is_same(TOUT, u16))
          C[(size_t)(row + i) * N + col] = f2b(v);
        else
          C[(size_t)(row + i) * N + col] = v;
      }
    }
  }
}

// standalone gemm256 (R5/R7-verified incl. EPI=1/float path): grid %8==0
template<int EPI, typename TOUT>
__global__ __launch_bounds__(256, 2)
void gemm256(const u16* __restrict__ A, const u16* __restrict__ Wb,
             const float* __restrict__ bias, const float* __restrict__ mask,
             TOUT* __restrict__ C, int M, int N, int K)
{
  __shared__ __align__(16) u16 L[36864];
  const int nwg = gridDim.x;
  const int tb = (blockIdx.x & 7) * (nwg >> 3) + (blockIdx.x >> 3);
  g256_body<EPI, TOUT>(A, Wb, bias, mask, C, N, K, tb, L);
}

// fused Q + KV GEMM (R9-verified, 222 us): 960 blocks = 768 Q + 192 KV.
__global__ __launch_bounds__(256, 2)
void gemm_fused(const u16* __restrict__ Aq, const u16* __restrict__ Bq,
                const float* __restrict__ bq, u16* __restrict__ Cq,
                const u16* __restrict__ Akv, const u16* __restrict__ Bkv,
                const float* __restrict__ bkv, u16* __restrict__ Ckv, int K)
{
  __shared__ __align__(16) u16 L[36864];
  const int b0 = blockIdx.x;
  if (b0 < 768) {
    const int tb = (b0 & 7) * 96 + (b0 >> 3);
    g256_body<0, u16>(Aq, Bq, bq, nullptr, Cq, 3072, K, tb, L);
  } else {
    const int b2 = b0 - 768;
    const int tb = (b2 & 7) * 24 + (b2 >> 3);
    g256_body<0, u16>(Akv, Bkv, bkv, nullptr, Ckv, 6144, K, tb, L);
  }
}

// =====================================================================
// Fallback mixed GEMM (W fp32 reg-staged cvt) — tier-3 only.
// =====================================================================
template<int EPI, typename TOUT>
__global__ __launch_bounds__(256)
void gemm_mixed(const u16* __restrict__ A, const float* __restrict__ W,
                const float* __restrict__ bias, const float* __restrict__ mask,
                TOUT* __restrict__ C, int M, int N, int K)
{
  __shared__ __align__(16) u16 lA[4096];
  __shared__ __align__(16) u16 lB[4096];
  const int tid = threadIdx.x, wave = tid >> 6, lane = tid & 63;
  const int nbx = N >> 7;
  const int brow = (blockIdx.x / nbx) << 7;
  const int bcol = (blockIdx.x % nbx) << 7;
  const int wr = wave >> 1, wc = wave & 1;

  f32x4 acc[4][4] = {};
  const u16* gA = A + (size_t)brow * K;
  const float* gB = W + (size_t)bcol * K;
  const int br = tid >> 1, bk0 = (tid & 1) << 4;
  const float* bsrc0 = gB + (size_t)br * K + bk0;
  u16* bdst = &lB[br * 32 + bk0];

  for (int tk = 0; tk < K; tk += 32) {
    #pragma unroll
    for (int j = 0; j < 2; ++j) {
      const int c = j * 256 + wave * 64 + lane;
      const int r = c >> 2, k8 = (c & 3) << 3;
      g2l16(gA + (size_t)r * K + tk + k8, (char*)lA + (size_t)(j * 256 + wave * 64) * 16);
    }
    {
      const float* src = bsrc0 + tk;
      #pragma unroll
      for (int j = 0; j < 4; ++j) {
        f32x4 v = *(const f32x4*)(src + 4 * j);
        u16x4 w; w.x = f2b(v.x); w.y = f2b(v.y); w.z = f2b(v.z); w.w = f2b(v.w);
        *(u16x4*)(bdst + 4 * j) = w;
      }
    }
    __syncthreads();

    bf16x8 af[4], bfr[4];
    #pragma unroll
    for (int m = 0; m < 4; ++m)
      af[m] = *(const bf16x8*)&lA[(wr * 64 + m * 16 + (lane & 15)) * 32 + ((lane >> 4) << 3)];
    #pragma unroll
    for (int n = 0; n < 4; ++n)
      bfr[n] = *(const bf16x8*)&lB[(wc * 64 + n * 16 + (lane & 15)) * 32 + ((lane >> 4) << 3)];
    #pragma unroll
    for (int m = 0; m < 4; ++m)
      #pragma unroll
      for (int n = 0; n < 4; ++n)
        acc[m][n] = __builtin_amdgcn_mfma_f32_16x16x32_bf16(af[m], bfr[n], acc[m][n], 0, 0, 0);
    __syncthreads();
  }

  #pragma unroll
  for (int m = 0; m < 4; ++m) {
    const int row = brow + wr * 64 + m * 16 + ((lane >> 4) << 2);
    #pragma unroll
    for (int n = 0; n < 4; ++n) {
      const int col = bcol + wc * 64 + n * 16 + (lane & 15);
      const float bv = bias[col];
      #pragma unroll
      for (int i = 0; i < 4; ++i) {
        float v = acc[m][n][i] + bv;
        if (EPI == 1) v *= mask[row + i];
        if constexpr (__is_same(TOUT, u16))
          C[(size_t)(row + i) * N + col] = f2b(v);
        else
          C[(size_t)(row + i) * N + col] = v;
      }
    }
  }
}

// =====================================================================
// attn_wcvt: blocks 0..767 MFMA attention (verified R7 body);
// blocks 768..1791 wo fp32->bf16.
// =====================================================================
__global__ __launch_bounds__(256)
void attn_wcvt(const u16* __restrict__ qb, const u16* __restrict__ kvb,
               const float* __restrict__ qw, const float* __restrict__ kw,
               u16* __restrict__ attnb,
               const float* __restrict__ wo, u16* __restrict__ wos)
{
  __shared__ __align__(16) u16 Kn[32 * 136];
  __shared__ __align__(16) u16 Vt[128 * 40];
  __shared__ __align__(16) u16 Pl[256 * 40];
  __shared__ __align__(16) u16 Ol[4][16 * 136];
  const int tid = threadIdx.x;
  if (blockIdx.x >= 768) {
    const int n4 = 3072 * 3072 / 4;
    for (int i = (blockIdx.x - 768) * 256 + tid; i < n4; i += 1024 * 256)
      cvt16(wo, wos, i);
    return;
  }
  const int wave = tid >> 6, lane = tid & 63;
  const int h = blockIdx.x % 24;
  const int bt = blockIdx.x / 24;

  {
    const int n = tid >> 3, sub = tid & 7;
    const size_t base = (size_t)(bt * 32 + n) * 6144 + (size_t)h * 128;
    const u16* kp = kvb + base + sub * 16;
    u16x8 k0 = *(const u16x8*)kp;
    u16x8 k1 = *(const u16x8*)(kp + 8);
    float kv_[16]; float ss = 0.f;
    #pragma unroll
    for (int j = 0; j < 8; ++j) { kv_[j] = b2f(k0[j]); kv_[8 + j] = b2f(k1[j]); }
    #pragma unroll
    for (int j = 0; j < 16; ++j) ss += kv_[j] * kv_[j];
    ss += __shfl_xor(ss, 1); ss += __shfl_xor(ss, 2); ss += __shfl_xor(ss, 4);
    const float krs = rsqrtf(ss * (1.f / 128.f) + 1e-6f);
    u16x8 w0, w1;
    #pragma unroll
    for (int j = 0; j < 8; ++j) {
      const int d = sub * 16 + j;
      w0[j] = f2b(kv_[j] * krs * kw[d] * qw[d]);
      w1[j] = f2b(kv_[8 + j] * krs * kw[d + 8] * qw[d + 8]);
    }
    *(u16x8*)&Kn[n * 136 + sub * 16] = w0;
    *(u16x8*)&Kn[n * 136 + sub * 16 + 8] = w1;
  }
  {
    const int k = tid >> 3, dc = (tid & 7) * 16;
    const u16* vp = kvb + (size_t)(bt * 32 + k) * 6144 + (size_t)h * 128 + 3072 + dc;
    u16x8 v0 = *(const u16x8*)vp;
    u16x8 v1 = *(const u16x8*)(vp + 8);
    #pragma unroll
    for (int j = 0; j < 8; ++j) {
      Vt[(dc + j) * 40 + k] = v0[j];
      Vt[(dc + 8 + j) * 40 + k] = v1[j];
    }
  }
  __syncthreads();

  const int q0 = wave * 64;
  const int lr = lane & 15, lg = lane >> 4;

  for (int m = 0; m < 4; ++m) {
    const int qrow = q0 + m * 16 + lr;
    const u16* qp = qb + (size_t)(bt * 256 + qrow) * 3072 + (size_t)h * 128 + lg * 8;
    bf16x8 qf[4];
    #pragma unroll
    for (int k = 0; k < 4; ++k) qf[k] = *(const bf16x8*)(qp + k * 32);
    float ss = 0.f;
    #pragma unroll
    for (int k = 0; k < 4; ++k)
      #pragma unroll
      for (int j = 0; j < 8; ++j) { const float f = b2f((u16)qf[k][j]); ss += f * f; }
    ss += __shfl_xor(ss, 16); ss += __shfl_xor(ss, 32);
    const float qsc = rsqrtf(ss * (1.f / 128.f) + 1e-6f) * 0.08838834764831845f;
    #pragma unroll
    for (int k = 0; k < 4; ++k)
      #pragma unroll
      for (int j = 0; j < 8; ++j)
        qf[k][j] = (short)f2b(b2f((u16)qf[k][j]) * qsc);

    f32x4 s0 = {0.f, 0.f, 0.f, 0.f}, s1 = {0.f, 0.f, 0.f, 0.f};
    #pragma unroll
    for (int k = 0; k < 4; ++k) {
      bf16x8 kb0 = *(const bf16x8*)&Kn[(lr) * 136 + k * 32 + lg * 8];
      bf16x8 kb1 = *(const bf16x8*)&Kn[(16 + lr) * 136 + k * 32 + lg * 8];
      s0 = __builtin_amdgcn_mfma_f32_16x16x32_bf16(qf[k], kb0, s0, 0, 0, 0);
      s1 = __builtin_amdgcn_mfma_f32_16x16x32_bf16(qf[k], kb1, s1, 0, 0, 0);
    }

    float mx[4], sm[4], e0[4], e1[4];
    #pragma unroll
    for (int i = 0; i < 4; ++i) mx[i] = fmaxf(s0[i], s1[i]);
    #pragma unroll
    for (int o = 1; o <= 8; o <<= 1)
      #pragma unroll
      for (int i = 0; i < 4; ++i) mx[i] = fmaxf(mx[i], __shfl_xor(mx[i], o));
    #pragma unroll
    for (int i = 0; i < 4; ++i) {
      e0[i] = __expf(s0[i] - mx[i]);
      e1[i] = __expf(s1[i] - mx[i]);
      sm[i] = e0[i] + e1[i];
    }
    #pragma unroll
    for (int o = 1; o <= 8; o <<= 1)
      #pragma unroll
      for (int i = 0; i < 4; ++i) sm[i] += __shfl_xor(sm[i], o);
    #pragma unroll
    for (int i = 0; i < 4; ++i) {
      const float inv = 1.f / sm[i];
      const int pr = (q0 + m * 16 + lg * 4 + i) * 40;
      Pl[pr + lr] = f2b(e0[i] * inv);
      Pl[pr + 16 + lr] = f2b(e1[i] * inv);
    }
    asm volatile("s_waitcnt lgkmcnt(0)" ::: "memory");
    __builtin_amdgcn_sched_barrier(0);

    bf16x8 pf = *(const bf16x8*)&Pl[(q0 + m * 16 + lr) * 40 + lg * 8];
    f32x4 o_[8];
    #pragma unroll
    for (int n = 0; n < 8; ++n) {
      bf16x8 vb = *(const bf16x8*)&Vt[(n * 16 + lr) * 40 + lg * 8];
      o_[n] = __builtin_amdgcn_mfma_f32_16x16x32_bf16(
                pf, vb, (f32x4){0.f, 0.f, 0.f, 0.f}, 0, 0, 0);
    }

    u16* ow = &Ol[wave][0];
    #pragma unroll
    for (int n = 0; n < 8; ++n)
      #pragma unroll
      for (int i = 0; i < 4; ++i)
        ow[(lg * 4 + i) * 136 + n * 16 + lr] = f2b(o_[n][i]);
    asm volatile("s_waitcnt lgkmcnt(0)" ::: "memory");
    __builtin_amdgcn_sched_barrier(0);
    const int r = lane >> 2, cc = (lane & 3) * 32;
    u16* gout = attnb + (size_t)(bt * 256 + q0 + m * 16 + r) * 3072 + (size_t)h * 128 + cc;
    #pragma unroll
    for (int c = 0; c < 4; ++c)
      *(u16x8*)(gout + c * 8) = *(const u16x8*)&ow[r * 136 + cc + c * 8];
    asm volatile("s_waitcnt lgkmcnt(0)" ::: "memory");
    __builtin_amdgcn_sched_barrier(0);
  }
}

// =====================================================================
extern "C" void kernel_launch(void* const* d_in, const int* in_sizes, int n_in,
                              void* d_out, int out_size, void* d_ws, size_t ws_size,
                              hipStream_t stream) {
  const float* x    = (const float*)d_in[0];
  const float* mv   = (const float*)d_in[1];
  const float* mask = (const float*)d_in[2];
  const float* wkv  = (const float*)d_in[3];
  const float* bkv  = (const float*)d_in[4];
  const float* wq   = (const float*)d_in[5];
  const float* bq   = (const float*)d_in[6];
  const float* wo   = (const float*)d_in[7];
  const float* bo   = (const float*)d_in[8];
  const float* qnw  = (const float*)d_in[9];
  const float* knw  = (const float*)d_in[10];
  float* out = (float*)d_out;

  char* ws = (char*)d_ws;

  if (ws_size >= 176160768u) {
    // tier-1 layout (R9-verified)
    u16* wqs  = (u16*)(ws);                  // 3072x3072 bf16
    u16* wkvs = (u16*)(ws + 18874368);       // 6144x3072 bf16
    u16* xf   = (u16*)(ws + 56623104);       // 8192x3072 bf16
    u16* xm   = (u16*)(ws + 106954752);      // 1024x3072 bf16
    u16* qbuf = (u16*)(ws + 113246208);      // 8192x3072 bf16
    u16* kvb  = (u16*)(ws + 163577856);      // 1024x6144 bf16 (end 176,160,768)
    u16* wos  = wqs;                         // reuse (dead after fused GEMM)

    prep_kernel<<<11264, 256, 0, stream>>>(x, mv, xf, xm, wq, wqs, wkv, wkvs);
    gemm_fused<<<960, 256, 0, stream>>>(xf, wqs, bq, qbuf, xm, wkvs, bkv, kvb, 3072);
    attn_wcvt<<<1792, 256, 0, stream>>>(qbuf, kvb, qnw, knw, xf, wo, wos);
    gemm256<1, float><<<768, 256, 0, stream>>>(xf, wos, bo, mask, out, 8192, 3072, 3072);
  } else if (ws_size >= 157286400u) {
    // tier-2
    u16* xf    = (u16*)(ws);
    u16* xm    = (u16*)(ws + 50331648);
    u16* qbuf  = (u16*)(ws + 56623104);
    u16* kvb   = (u16*)(ws + 106954752);
    u16* wslab = (u16*)(ws + 119537664);

    prep_kernel<<<9216, 256, 0, stream>>>(x, mv, xf, xm, wq, wslab, wkv, wslab);
    wcvt_kernel<<<2048, 256, 0, stream>>>(wq, wslab, 3072 * 3072 / 4);
    gemm256<0, u16><<<768, 256, 0, stream>>>(xf, wslab, bq, nullptr, qbuf, 8192, 3072, 3072);
    wcvt_kernel<<<2048, 256, 0, stream>>>(wkv, wslab, 6144 * 3072 / 4);
    gemm256<0, u16><<<192, 256, 0, stream>>>(xm, wslab, bkv, nullptr, kvb, 1024, 6144, 3072);
    attn_wcvt<<<768, 256, 0, stream>>>(qbuf, kvb, qnw, knw, xf, wo, wslab);
    wcvt_kernel<<<2048, 256, 0, stream>>>(wo, wslab, 3072 * 3072 / 4);
    gemm256<1, float><<<768, 256, 0, stream>>>(xf, wslab, bo, mask, out, 8192, 3072, 3072);
  } else {
    // tier-3: mixed fallback
    u16* xf   = (u16*)(ws);
    u16* xm   = (u16*)(ws + 50331648);
    u16* qbuf = (u16*)(ws + 56623104);
    u16* kvb  = (u16*)(ws + 106954752);

    prep_kernel<<<9216, 256, 0, stream>>>(x, mv, xf, xm, wq, xf, wkv, xf);
    gemm_mixed<0, u16><<<1536, 256, 0, stream>>>(xf, wq, bq, nullptr, qbuf, 8192, 3072, 3072);
    gemm_mixed<0, u16><<<384, 256, 0, stream>>>(xm, wkv, bkv, nullptr, kvb, 1024, 6144, 3072);
    attn_wcvt<<<768, 256, 0, stream>>>(qbuf, kvb, qnw, knw, xf, wo, xf);
    gemm_mixed<1, float><<<1536, 256, 0, stream>>>(xf, wo, bo, mask, out, 8192, 3072, 3072);
  }
}

// Round 16
// 456.538 us; speedup vs baseline: 1.1086x; 1.0105x over previous
//
#include <hip/hip_runtime.h>
#include <math.h>

typedef unsigned short u16;
typedef unsigned int u32;
typedef short bf16x8 __attribute__((ext_vector_type(8)));
typedef float f32x4 __attribute__((ext_vector_type(4)));
typedef u16 u16x4 __attribute__((ext_vector_type(4)));
typedef u16 u16x8 __attribute__((ext_vector_type(8)));
typedef u32 u32x4 __attribute__((ext_vector_type(4)));

// ---------- bf16 <-> f32 helpers ----------
static __device__ __forceinline__ float b2f(u16 u) {
  union { u32 i; float f; } v; v.i = ((u32)u) << 16; return v.f;
}
static __device__ __forceinline__ u16 f2b(float f) {
  union { float f; u32 i; } v; v.f = f;
  u32 r = v.i + 0x7fffu + ((v.i >> 16) & 1u);
  return (u16)(r >> 16);
}
static __device__ __forceinline__ void cvt16(const float* src, u16* dst, int i) {
  f32x4 v = *(const f32x4*)(src + (size_t)i * 4);
  u16x4 w; w.x = f2b(v.x); w.y = f2b(v.y); w.z = f2b(v.z); w.w = f2b(v.w);
  *(u16x4*)(dst + (size_t)i * 4) = w;
}

// ---------- async global -> LDS, 16B per lane ----------
static __device__ __forceinline__ void g2l16(const void* g, void* l) {
  typedef __attribute__((address_space(1))) const void gvoid;
  typedef __attribute__((address_space(3))) void lvoid;
  __builtin_amdgcn_global_load_lds((gvoid*)g, (lvoid*)l, 16, 0, 0);
}

// =====================================================================
// Standalone weight convert (tier-2/3).
// =====================================================================
__global__ __launch_bounds__(256)
void wcvt_kernel(const float* __restrict__ src, u16* __restrict__ dst, int n4)
{
  for (int i = blockIdx.x * 256 + threadIdx.x; i < n4; i += gridDim.x * 256)
    cvt16(src, dst, i);
}

// =====================================================================
// prep: blocks 0..9215 LayerNorm; 9216..10239 wq cvt; 10240..11263 wkv cvt.
// =====================================================================
__global__ __launch_bounds__(256)
void prep_kernel(const float* __restrict__ x, const float* __restrict__ mv,
                 u16* __restrict__ xf, u16* __restrict__ xm,
                 const float* __restrict__ wq, u16* __restrict__ wqs,
                 const float* __restrict__ wkv, u16* __restrict__ wkvs)
{
  const int b = blockIdx.x, tid = threadIdx.x;
  if (b >= 9216) {
    if (b < 10240) {
      const int n4 = 3072 * 3072 / 4;
      for (int i = (b - 9216) * 256 + tid; i < n4; i += 1024 * 256) cvt16(wq, wqs, i);
    } else {
      const int n4 = 6144 * 3072 / 4;
      for (int i = (b - 10240) * 256 + tid; i < n4; i += 1024 * 256) cvt16(wkv, wkvs, i);
    }
    return;
  }
  const float* src; u16* dst;
  if (b < 8192) { src = x + (size_t)b * 3072;          dst = xf + (size_t)b * 3072; }
  else          { src = mv + (size_t)(b - 8192) * 3072; dst = xm + (size_t)(b - 8192) * 3072; }

  f32x4 vals[3];
  #pragma unroll
  for (int i = 0; i < 3; ++i) vals[i] = *(const f32x4*)(src + tid * 4 + i * 1024);

  float s1 = 0.f, s2 = 0.f;
  #pragma unroll
  for (int i = 0; i < 3; ++i) {
    f32x4 v = vals[i];
    s1 += v.x + v.y + v.z + v.w;
    s2 += v.x * v.x + v.y * v.y + v.z * v.z + v.w * v.w;
  }
  #pragma unroll
  for (int o = 32; o > 0; o >>= 1) { s1 += __shfl_down(s1, o); s2 += __shfl_down(s2, o); }
  __shared__ float r1[4], r2[4];
  const int wv = tid >> 6, ln = tid & 63;
  if (ln == 0) { r1[wv] = s1; r2[wv] = s2; }
  __syncthreads();
  const float t1 = r1[0] + r1[1] + r1[2] + r1[3];
  const float t2 = r2[0] + r2[1] + r2[2] + r2[3];
  const float mu = t1 * (1.f / 3072.f);
  const float rs = rsqrtf(t2 * (1.f / 3072.f) - mu * mu + 1e-6f);
  #pragma unroll
  for (int i = 0; i < 3; ++i) {
    f32x4 v = vals[i]; u16x4 w;
    w.x = f2b((v.x - mu) * rs); w.y = f2b((v.y - mu) * rs);
    w.z = f2b((v.z - mu) * rs); w.w = f2b((v.w - mu) * rs);
    *(u16x4*)(dst + tid * 4 + i * 1024) = w;
  }
}

// =====================================================================
// g256_body: R5-verified pipelined GEMM body. 256x128 tile, BK=32,
// 4 waves (2x2), 3-buf LDS rotation (72 KB), counted vmcnt(6),
// XOR-swizzled LDS via pre-swizzled global source, setprio.
// Measured: 177 us / 873 TF on 8192x3072x3072, bank conflicts 0.
// =====================================================================
template<int EPI, typename TOUT>
static __device__ __forceinline__ void g256_body(
    const u16* __restrict__ A, const u16* __restrict__ Wb,
    const float* __restrict__ bias, const float* __restrict__ mask,
    TOUT* __restrict__ C, int N, int K, int tb, u16* L)
{
  const int tid = threadIdx.x, wave = tid >> 6, lane = tid & 63;
  const int nbx = N >> 7;
  const int brow = (tb / nbx) << 8;
  const int bcol = (tb % nbx) << 7;
  const int wr = wave >> 1, wc = wave & 1;

  const u16* gA = A + (size_t)brow * K;
  const u16* gB = Wb + (size_t)bcol * K;

  const int srow = tid >> 2;
  const int scol = 8 * ((lane & 3) ^ ((lane >> 3) & 3));
  const int rcoff = 8 * ((lane >> 4) ^ ((lane >> 1) & 3));

  f32x4 acc[8][4] = {};

  auto STAGE = [&](int b, int tk) {
    u16* bufA = &L[b * 12288];
    u16* bufB = bufA + 8192;
    const u16* srcA = gA + tk + scol;
    const u16* srcB = gB + tk + scol;
    #pragma unroll
    for (int j = 0; j < 4; ++j)
      g2l16(srcA + (size_t)(j * 64 + srow) * K, bufA + (j * 64 + wave * 16) * 32);
    #pragma unroll
    for (int j = 0; j < 2; ++j)
      g2l16(srcB + (size_t)(j * 64 + srow) * K, bufB + (j * 64 + wave * 16) * 32);
  };

  auto COMPUTE = [&](int b) {
    const u16* bufA = &L[b * 12288];
    const u16* bufB = bufA + 8192;
    bf16x8 af[8], bfv[4];
    #pragma unroll
    for (int m = 0; m < 8; ++m)
      af[m] = *(const bf16x8*)&bufA[(wr * 128 + m * 16 + (lane & 15)) * 32 + rcoff];
    #pragma unroll
    for (int n = 0; n < 4; ++n)
      bfv[n] = *(const bf16x8*)&bufB[(wc * 64 + n * 16 + (lane & 15)) * 32 + rcoff];
    __builtin_amdgcn_s_setprio(1);
    #pragma unroll
    for (int m = 0; m < 8; ++m)
      #pragma unroll
      for (int n = 0; n < 4; ++n)
        acc[m][n] = __builtin_amdgcn_mfma_f32_16x16x32_bf16(af[m], bfv[n], acc[m][n], 0, 0, 0);
    __builtin_amdgcn_s_setprio(0);
  };

  STAGE(0, 0);
  STAGE(1, 32);
  asm volatile("s_waitcnt vmcnt(6)" ::: "memory");
  __builtin_amdgcn_s_barrier();
  __builtin_amdgcn_sched_barrier(0);

  const int NT = K >> 5;
  int cur = 0;
  for (int t = 0; t < NT; ++t) {
    const bool pf = (t + 2) < NT;
    if (pf) {
      int nb = cur + 2; if (nb >= 3) nb -= 3;
      STAGE(nb, (t + 2) << 5);
    }
    COMPUTE(cur);
    if (pf) asm volatile("s_waitcnt vmcnt(6)" ::: "memory");
    else    asm volatile("s_waitcnt vmcnt(0)" ::: "memory");
    __builtin_amdgcn_s_barrier();
    __builtin_amdgcn_sched_barrier(0);
    if (++cur == 3) cur = 0;
  }

  #pragma unroll
  for (int m = 0; m < 8; ++m) {
    const int row = brow + wr * 128 + m * 16 + ((lane >> 4) << 2);
    #pragma unroll
    for (int n = 0; n < 4; ++n) {
      const int col = bcol + wc * 64 + n * 16 + (lane & 15);
      const float bv = bias[col];
      #pragma unroll
      for (int i = 0; i < 4; ++i) {
        float v = acc[m][n][i] + bv;
        if (EPI == 1) v *= mask[row + i];
        if constexpr (__is_same(TOUT, u16))
          C[(size_t)(row + i) * N + col] = f2b(v);
        else
          C[(size_t)(row + i) * N + col] = v;
      }
    }
  }
}

// standalone gemm256 (R5/R7-verified incl. EPI=1/float path): grid %8==0
template<int EPI, typename TOUT>
__global__ __launch_bounds__(256, 2)
void gemm256(const u16* __restrict__ A, const u16* __restrict__ Wb,
             const float* __restrict__ bias, const float* __restrict__ mask,
             TOUT* __restrict__ C, int M, int N, int K)
{
  __shared__ __align__(16) u16 L[36864];
  const int nwg = gridDim.x;
  const int tb = (blockIdx.x & 7) * (nwg >> 3) + (blockIdx.x >> 3);
  g256_body<EPI, TOUT>(A, Wb, bias, mask, C, N, K, tb, L);
}

// fused Q + KV GEMM (R9/R14-verified, 217 us): 960 blocks = 768 Q + 192 KV.
__global__ __launch_bounds__(256, 2)
void gemm_fused(const u16* __restrict__ Aq, const u16* __restrict__ Bq,
                const float* __restrict__ bq, u16* __restrict__ Cq,
                const u16* __restrict__ Akv, const u16* __restrict__ Bkv,
                const float* __restrict__ bkv, u16* __restrict__ Ckv, int K)
{
  __shared__ __align__(16) u16 L[36864];
  const int b0 = blockIdx.x;
  if (b0 < 768) {
    const int tb = (b0 & 7) * 96 + (b0 >> 3);
    g256_body<0, u16>(Aq, Bq, bq, nullptr, Cq, 3072, K, tb, L);
  } else {
    const int b2 = b0 - 768;
    const int tb = (b2 & 7) * 24 + (b2 >> 3);
    g256_body<0, u16>(Akv, Bkv, bkv, nullptr, Ckv, 6144, K, tb, L);
  }
}

// =====================================================================
// Fallback mixed GEMM (W fp32 reg-staged cvt) — tier-3 only.
// =====================================================================
template<int EPI, typename TOUT>
__global__ __launch_bounds__(256)
void gemm_mixed(const u16* __restrict__ A, const float* __restrict__ W,
                const float* __restrict__ bias, const float* __restrict__ mask,
                TOUT* __restrict__ C, int M, int N, int K)
{
  __shared__ __align__(16) u16 lA[4096];
  __shared__ __align__(16) u16 lB[4096];
  const int tid = threadIdx.x, wave = tid >> 6, lane = tid & 63;
  const int nbx = N >> 7;
  const int brow = (blockIdx.x / nbx) << 7;
  const int bcol = (blockIdx.x % nbx) << 7;
  const int wr = wave >> 1, wc = wave & 1;

  f32x4 acc[4][4] = {};
  const u16* gA = A + (size_t)brow * K;
  const float* gB = W + (size_t)bcol * K;
  const int br = tid >> 1, bk0 = (tid & 1) << 4;
  const float* bsrc0 = gB + (size_t)br * K + bk0;
  u16* bdst = &lB[br * 32 + bk0];

  for (int tk = 0; tk < K; tk += 32) {
    #pragma unroll
    for (int j = 0; j < 2; ++j) {
      const int c = j * 256 + wave * 64 + lane;
      const int r = c >> 2, k8 = (c & 3) << 3;
      g2l16(gA + (size_t)r * K + tk + k8, (char*)lA + (size_t)(j * 256 + wave * 64) * 16);
    }
    {
      const float* src = bsrc0 + tk;
      #pragma unroll
      for (int j = 0; j < 4; ++j) {
        f32x4 v = *(const f32x4*)(src + 4 * j);
        u16x4 w; w.x = f2b(v.x); w.y = f2b(v.y); w.z = f2b(v.z); w.w = f2b(v.w);
        *(u16x4*)(bdst + 4 * j) = w;
      }
    }
    __syncthreads();

    bf16x8 af[4], bfr[4];
    #pragma unroll
    for (int m = 0; m < 4; ++m)
      af[m] = *(const bf16x8*)&lA[(wr * 64 + m * 16 + (lane & 15)) * 32 + ((lane >> 4) << 3)];
    #pragma unroll
    for (int n = 0; n < 4; ++n)
      bfr[n] = *(const bf16x8*)&lB[(wc * 64 + n * 16 + (lane & 15)) * 32 + ((lane >> 4) << 3)];
    #pragma unroll
    for (int m = 0; m < 4; ++m)
      #pragma unroll
      for (int n = 0; n < 4; ++n)
        acc[m][n] = __builtin_amdgcn_mfma_f32_16x16x32_bf16(af[m], bfr[n], acc[m][n], 0, 0, 0);
    __syncthreads();
  }

  #pragma unroll
  for (int m = 0; m < 4; ++m) {
    const int row = brow + wr * 64 + m * 16 + ((lane >> 4) << 2);
    #pragma unroll
    for (int n = 0; n < 4; ++n) {
      const int col = bcol + wc * 64 + n * 16 + (lane & 15);
      const float bv = bias[col];
      #pragma unroll
      for (int i = 0; i < 4; ++i) {
        float v = acc[m][n][i] + bv;
        if (EPI == 1) v *= mask[row + i];
        if constexpr (__is_same(TOUT, u16))
          C[(size_t)(row + i) * N + col] = f2b(v);
        else
          C[(size_t)(row + i) * N + col] = v;
      }
    }
  }
}

// =====================================================================
// attn_wcvt: blocks 0..767 MFMA attention (verified R7 body);
// blocks 768..1791 wo fp32->bf16.
// =====================================================================
__global__ __launch_bounds__(256)
void attn_wcvt(const u16* __restrict__ qb, const u16* __restrict__ kvb,
               const float* __restrict__ qw, const float* __restrict__ kw,
               u16* __restrict__ attnb,
               const float* __restrict__ wo, u16* __restrict__ wos)
{
  __shared__ __align__(16) u16 Kn[32 * 136];
  __shared__ __align__(16) u16 Vt[128 * 40];
  __shared__ __align__(16) u16 Pl[256 * 40];
  __shared__ __align__(16) u16 Ol[4][16 * 136];
  const int tid = threadIdx.x;
  if (blockIdx.x >= 768) {
    const int n4 = 3072 * 3072 / 4;
    for (int i = (blockIdx.x - 768) * 256 + tid; i < n4; i += 1024 * 256)
      cvt16(wo, wos, i);
    return;
  }
  const int wave = tid >> 6, lane = tid & 63;
  const int h = blockIdx.x % 24;
  const int bt = blockIdx.x / 24;

  {
    const int n = tid >> 3, sub = tid & 7;
    const size_t base = (size_t)(bt * 32 + n) * 6144 + (size_t)h * 128;
    const u16* kp = kvb + base + sub * 16;
    u16x8 k0 = *(const u16x8*)kp;
    u16x8 k1 = *(const u16x8*)(kp + 8);
    float kv_[16]; float ss = 0.f;
    #pragma unroll
    for (int j = 0; j < 8; ++j) { kv_[j] = b2f(k0[j]); kv_[8 + j] = b2f(k1[j]); }
    #pragma unroll
    for (int j = 0; j < 16; ++j) ss += kv_[j] * kv_[j];
    ss += __shfl_xor(ss, 1); ss += __shfl_xor(ss, 2); ss += __shfl_xor(ss, 4);
    const float krs = rsqrtf(ss * (1.f / 128.f) + 1e-6f);
    u16x8 w0, w1;
    #pragma unroll
    for (int j = 0; j < 8; ++j) {
      const int d = sub * 16 + j;
      w0[j] = f2b(kv_[j] * krs * kw[d] * qw[d]);
      w1[j] = f2b(kv_[8 + j] * krs * kw[d + 8] * qw[d + 8]);
    }
    *(u16x8*)&Kn[n * 136 + sub * 16] = w0;
    *(u16x8*)&Kn[n * 136 + sub * 16 + 8] = w1;
  }
  {
    const int k = tid >> 3, dc = (tid & 7) * 16;
    const u16* vp = kvb + (size_t)(bt * 32 + k) * 6144 + (size_t)h * 128 + 3072 + dc;
    u16x8 v0 = *(const u16x8*)vp;
    u16x8 v1 = *(const u16x8*)(vp + 8);
    #pragma unroll
    for (int j = 0; j < 8; ++j) {
      Vt[(dc + j) * 40 + k] = v0[j];
      Vt[(dc + 8 + j) * 40 + k] = v1[j];
    }
  }
  __syncthreads();

  const int q0 = wave * 64;
  const int lr = lane & 15, lg = lane >> 4;

  for (int m = 0; m < 4; ++m) {
    const int qrow = q0 + m * 16 + lr;
    const u16* qp = qb + (size_t)(bt * 256 + qrow) * 3072 + (size_t)h * 128 + lg * 8;
    bf16x8 qf[4];
    #pragma unroll
    for (int k = 0; k < 4; ++k) qf[k] = *(const bf16x8*)(qp + k * 32);
    float ss = 0.f;
    #pragma unroll
    for (int k = 0; k < 4; ++k)
      #pragma unroll
      for (int j = 0; j < 8; ++j) { const float f = b2f((u16)qf[k][j]); ss += f * f; }
    ss += __shfl_xor(ss, 16); ss += __shfl_xor(ss, 32);
    const float qsc = rsqrtf(ss * (1.f / 128.f) + 1e-6f) * 0.08838834764831845f;
    #pragma unroll
    for (int k = 0; k < 4; ++k)
      #pragma unroll
      for (int j = 0; j < 8; ++j)
        qf[k][j] = (short)f2b(b2f((u16)qf[k][j]) * qsc);

    f32x4 s0 = {0.f, 0.f, 0.f, 0.f}, s1 = {0.f, 0.f, 0.f, 0.f};
    #pragma unroll
    for (int k = 0; k < 4; ++k) {
      bf16x8 kb0 = *(const bf16x8*)&Kn[(lr) * 136 + k * 32 + lg * 8];
      bf16x8 kb1 = *(const bf16x8*)&Kn[(16 + lr) * 136 + k * 32 + lg * 8];
      s0 = __builtin_amdgcn_mfma_f32_16x16x32_bf16(qf[k], kb0, s0, 0, 0, 0);
      s1 = __builtin_amdgcn_mfma_f32_16x16x32_bf16(qf[k], kb1, s1, 0, 0, 0);
    }

    float mx[4], sm[4], e0[4], e1[4];
    #pragma unroll
    for (int i = 0; i < 4; ++i) mx[i] = fmaxf(s0[i], s1[i]);
    #pragma unroll
    for (int o = 1; o <= 8; o <<= 1)
      #pragma unroll
      for (int i = 0; i < 4; ++i) mx[i] = fmaxf(mx[i], __shfl_xor(mx[i], o));
    #pragma unroll
    for (int i = 0; i < 4; ++i) {
      e0[i] = __expf(s0[i] - mx[i]);
      e1[i] = __expf(s1[i] - mx[i]);
      sm[i] = e0[i] + e1[i];
    }
    #pragma unroll
    for (int o = 1; o <= 8; o <<= 1)
      #pragma unroll
      for (int i = 0; i < 4; ++i) sm[i] += __shfl_xor(sm[i], o);
    #pragma unroll
    for (int i = 0; i < 4; ++i) {
      const float inv = 1.f / sm[i];
      const int pr = (q0 + m * 16 + lg * 4 + i) * 40;
      Pl[pr + lr] = f2b(e0[i] * inv);
      Pl[pr + 16 + lr] = f2b(e1[i] * inv);
    }
    asm volatile("s_waitcnt lgkmcnt(0)" ::: "memory");
    __builtin_amdgcn_sched_barrier(0);

    bf16x8 pf = *(const bf16x8*)&Pl[(q0 + m * 16 + lr) * 40 + lg * 8];
    f32x4 o_[8];
    #pragma unroll
    for (int n = 0; n < 8; ++n) {
      bf16x8 vb = *(const bf16x8*)&Vt[(n * 16 + lr) * 40 + lg * 8];
      o_[n] = __builtin_amdgcn_mfma_f32_16x16x32_bf16(
                pf, vb, (f32x4){0.f, 0.f, 0.f, 0.f}, 0, 0, 0);
    }

    u16* ow = &Ol[wave][0];
    #pragma unroll
    for (int n = 0; n < 8; ++n)
      #pragma unroll
      for (int i = 0; i < 4; ++i)
        ow[(lg * 4 + i) * 136 + n * 16 + lr] = f2b(o_[n][i]);
    asm volatile("s_waitcnt lgkmcnt(0)" ::: "memory");
    __builtin_amdgcn_sched_barrier(0);
    const int r = lane >> 2, cc = (lane & 3) * 32;
    u16* gout = attnb + (size_t)(bt * 256 + q0 + m * 16 + r) * 3072 + (size_t)h * 128 + cc;
    #pragma unroll
    for (int c = 0; c < 4; ++c)
      *(u16x8*)(gout + c * 8) = *(const u16x8*)&ow[r * 136 + cc + c * 8];
    asm volatile("s_waitcnt lgkmcnt(0)" ::: "memory");
    __builtin_amdgcn_sched_barrier(0);
  }
}

// =====================================================================
extern "C" void kernel_launch(void* const* d_in, const int* in_sizes, int n_in,
                              void* d_out, int out_size, void* d_ws, size_t ws_size,
                              hipStream_t stream) {
  const float* x    = (const float*)d_in[0];
  const float* mv   = (const float*)d_in[1];
  const float* mask = (const float*)d_in[2];
  const float* wkv  = (const float*)d_in[3];
  const float* bkv  = (const float*)d_in[4];
  const float* wq   = (const float*)d_in[5];
  const float* bq   = (const float*)d_in[6];
  const float* wo   = (const float*)d_in[7];
  const float* bo   = (const float*)d_in[8];
  const float* qnw  = (const float*)d_in[9];
  const float* knw  = (const float*)d_in[10];
  float* out = (float*)d_out;

  char* ws = (char*)d_ws;

  if (ws_size >= 176160768u) {
    // tier-1 layout (R14-verified best: 461 us)
    u16* wqs  = (u16*)(ws);                  // 3072x3072 bf16
    u16* wkvs = (u16*)(ws + 18874368);       // 6144x3072 bf16
    u16* xf   = (u16*)(ws + 56623104);       // 8192x3072 bf16
    u16* xm   = (u16*)(ws + 106954752);      // 1024x3072 bf16
    u16* qbuf = (u16*)(ws + 113246208);      // 8192x3072 bf16
    u16* kvb  = (u16*)(ws + 163577856);      // 1024x6144 bf16 (end 176,160,768)
    u16* wos  = wqs;                         // reuse (dead after fused GEMM)

    prep_kernel<<<11264, 256, 0, stream>>>(x, mv, xf, xm, wq, wqs, wkv, wkvs);
    gemm_fused<<<960, 256, 0, stream>>>(xf, wqs, bq, qbuf, xm, wkvs, bkv, kvb, 3072);
    attn_wcvt<<<1792, 256, 0, stream>>>(qbuf, kvb, qnw, knw, xf, wo, wos);
    gemm256<1, float><<<768, 256, 0, stream>>>(xf, wos, bo, mask, out, 8192, 3072, 3072);
  } else if (ws_size >= 157286400u) {
    // tier-2
    u16* xf    = (u16*)(ws);
    u16* xm    = (u16*)(ws + 50331648);
    u16* qbuf  = (u16*)(ws + 56623104);
    u16* kvb   = (u16*)(ws + 106954752);
    u16* wslab = (u16*)(ws + 119537664);

    prep_kernel<<<9216, 256, 0, stream>>>(x, mv, xf, xm, wq, wslab, wkv, wslab);
    wcvt_kernel<<<2048, 256, 0, stream>>>(wq, wslab, 3072 * 3072 / 4);
    gemm256<0, u16><<<768, 256, 0, stream>>>(xf, wslab, bq, nullptr, qbuf, 8192, 3072, 3072);
    wcvt_kernel<<<2048, 256, 0, stream>>>(wkv, wslab, 6144 * 3072 / 4);
    gemm256<0, u16><<<192, 256, 0, stream>>>(xm, wslab, bkv, nullptr, kvb, 1024, 6144, 3072);
    attn_wcvt<<<768, 256, 0, stream>>>(qbuf, kvb, qnw, knw, xf, wo, wslab);
    wcvt_kernel<<<2048, 256, 0, stream>>>(wo, wslab, 3072 * 3072 / 4);
    gemm256<1, float><<<768, 256, 0, stream>>>(xf, wslab, bo, mask, out, 8192, 3072, 3072);
  } else {
    // tier-3: mixed fallback
    u16* xf   = (u16*)(ws);
    u16* xm   = (u16*)(ws + 50331648);
    u16* qbuf = (u16*)(ws + 56623104);
    u16* kvb  = (u16*)(ws + 106954752);

    prep_kernel<<<9216, 256, 0, stream>>>(x, mv, xf, xm, wq, xf, wkv, xf);
    gemm_mixed<0, u16><<<1536, 256, 0, stream>>>(xf, wq, bq, nullptr, qbuf, 8192, 3072, 3072);
    gemm_mixed<0, u16><<<384, 256, 0, stream>>>(xm, wkv, bkv, nullptr, kvb, 1024, 6144, 3072);
    attn_wcvt<<<768, 256, 0, stream>>>(qbuf, kvb, qnw, knw, xf, wo, xf);
    gemm_mixed<1, float><<<1536, 256, 0, stream>>>(xf, wo, bo, mask, out, 8192, 3072, 3072);
  }
}